// Round 11
// baseline (25.248 us; speedup 1.0000x reference)
//
#include <hip/hip_runtime.h>
#include <math.h>

#define N_PTS 1024
#define D 128
#define QL 400
#define PLD 1200            // 3*QL
#define SQRT_D_INV 0.08838834764831845f

typedef __attribute__((ext_vector_type(8))) short bf16x8;
typedef __attribute__((ext_vector_type(4))) float f32x4;
typedef unsigned short u16;

#define GLOBAL_AS __attribute__((address_space(1)))
#define LDS_AS    __attribute__((address_space(3)))

__device__ __forceinline__ u16 f2bf(float x) {
    union { float f; unsigned u; } v; v.f = x;
    unsigned r = v.u + 0x7fff + ((v.u >> 16) & 1);   // RNE
    return (u16)(r >> 16);
}
__device__ __forceinline__ float b2f(u16 h) {
    union { unsigned u; float f; } v; v.u = ((unsigned)h) << 16;
    return v.f;
}

// ------------------------------------------------------------------
// prep2_kernel: ONE dispatch, two independent roles:
//  blocks [0,192):   qkv 32x64 tiles -> qb(1/sqrtD)/kb/vT
//  blocks [192,496): P-role (R10-proven): G-tile = Tcat@Wk^T local,
//                    P-tile = X@G^T + bP, scaled -> Pb bf16
// ------------------------------------------------------------------
__global__ __launch_bounds__(256) void prep2_kernel(
    const float* __restrict__ features, const float* __restrict__ W,
    const float* __restrict__ bias,
    const float* __restrict__ tx, const float* __restrict__ ty,
    const float* __restrict__ tz,
    u16* __restrict__ qb, u16* __restrict__ kb, u16* __restrict__ vT,
    u16* __restrict__ Pb, unsigned* __restrict__ cnt)
{
    __shared__ __align__(16) u16 smem[24704];   // 49.4 KB
    const int tid = threadIdx.x;
    const int bx = blockIdx.x;
    const int wave = tid >> 6, lane = tid & 63;
    const int wr = wave >> 1, wc = wave & 1;
    const int l15 = lane & 15, l4 = lane >> 4;

    if (bx == 0 && tid < 64) cnt[tid] = 0u;

    if (bx < 192) {
        // ---------------- qkv role: 32x64 tiles ----------------
        u16* As = smem;            // 32 x 128
        u16* Bs = smem + 4096;     // 64 x 128
        const int bm = (bx / 6) * 32;
        const int bn = (bx % 6) * 64;

        #pragma unroll
        for (int r0 = 0; r0 < 2; ++r0) {
            int unit = r0 * 256 + tid;
            int row = unit >> 4, c16 = unit & 15;
            const float* ga = features + (size_t)(bm + row) * D + c16 * 8;
            float4 a0 = *(const float4*)ga;
            float4 a1 = *(const float4*)(ga + 4);
            u16 h[8] = {f2bf(a0.x), f2bf(a0.y), f2bf(a0.z), f2bf(a0.w),
                        f2bf(a1.x), f2bf(a1.y), f2bf(a1.z), f2bf(a1.w)};
            *(bf16x8*)(As + row * 128 + ((c16 ^ (row & 7)) * 8)) = *(bf16x8*)h;
        }
        #pragma unroll
        for (int r2 = 0; r2 < 8; ++r2) {
            int k = r2 * 16 + (tid >> 4);
            int nl = (tid & 15) * 4;
            float4 w4 = *(const float4*)&W[(size_t)k * 384 + bn + nl];
            float wv[4] = {w4.x, w4.y, w4.z, w4.w};
            #pragma unroll
            for (int e = 0; e < 4; ++e) {
                int n = nl + e;
                Bs[n * 128 + (((k >> 3) ^ (n & 7)) << 3) + (k & 7)] = f2bf(wv[e]);
            }
        }
        __syncthreads();

        f32x4 acc[2] = {};
        #pragma unroll
        for (int ks = 0; ks < 4; ++ks) {
            bf16x8 a, b[2];
            int arow = wr * 16 + l15;
            int c16 = ks * 4 + l4;
            a = *(const bf16x8*)(As + arow * 128 + ((c16 ^ (arow & 7)) * 8));
            #pragma unroll
            for (int n = 0; n < 2; ++n) {
                int row = wc * 32 + n * 16 + l15;
                b[n] = *(const bf16x8*)(Bs + row * 128 + ((c16 ^ (row & 7)) * 8));
            }
            #pragma unroll
            for (int n = 0; n < 2; ++n)
                acc[n] = __builtin_amdgcn_mfma_f32_16x16x32_bf16(
                    a, b[n], acc[n], 0, 0, 0);
        }

        #pragma unroll
        for (int n = 0; n < 2; ++n)
            #pragma unroll
            for (int r = 0; r < 4; ++r) {
                int grow = bm + wr * 16 + l4 * 4 + r;
                int gcol = bn + wc * 32 + n * 16 + l15;
                float val = acc[n][r] + bias[gcol];
                int reg = gcol >> 7, lc = gcol & 127;
                if (reg == 0)      qb[grow * D + lc] = f2bf(val * SQRT_D_INV);
                else if (reg == 1) kb[grow * D + lc] = f2bf(val);
                else               vT[(size_t)lc * N_PTS + grow] = f2bf(val);
            }
        return;
    }

    // ---------------- P role (R10-proven) ----------------
    const int t = bx - 192;
    const int ib = t / 19, jb = t % 19;
    const int bm = ib * 64, bn = jb * 64;
    u16* Ta = smem;                         // Tcat tile 64x128; later X tile
    u16* Wb = smem + 8192;                  // Wk 128x128; later G 64x128
    float* bPl = (float*)(smem + 24576);    // 64 f32

    #pragma unroll
    for (int r0 = 0; r0 < 4; ++r0) {
        int unit = r0 * 256 + tid;
        int row = unit >> 4, c16 = unit & 15;
        int c = bn + row; if (c > PLD - 1) c = PLD - 1;
        int sec = c / QL, rr = c - sec * QL;
        const float* tsec = (sec == 0) ? tx : ((sec == 1) ? ty : tz);
        const float* ga = tsec + QL * D + rr * D + c16 * 8;
        float4 a0 = *(const float4*)ga;
        float4 a1 = *(const float4*)(ga + 4);
        u16 h[8] = {f2bf(a0.x), f2bf(a0.y), f2bf(a0.z), f2bf(a0.w),
                    f2bf(a1.x), f2bf(a1.y), f2bf(a1.z), f2bf(a1.w)};
        *(bf16x8*)(Ta + row * 128 + ((c16 ^ (row & 7)) * 8)) = *(bf16x8*)h;
    }
    #pragma unroll
    for (int r0 = 0; r0 < 8; ++r0) {
        int unit = r0 * 256 + tid;
        int e = unit >> 4, c16 = unit & 15;
        const float* ga = W + (size_t)e * 384 + 128 + c16 * 8;
        float4 a0 = *(const float4*)ga;
        float4 a1 = *(const float4*)(ga + 4);
        u16 h[8] = {f2bf(a0.x), f2bf(a0.y), f2bf(a0.z), f2bf(a0.w),
                    f2bf(a1.x), f2bf(a1.y), f2bf(a1.z), f2bf(a1.w)};
        *(bf16x8*)(Wb + e * 128 + ((c16 ^ (e & 7)) * 8)) = *(bf16x8*)h;
    }
    __syncthreads();

    // G-GEMM: G[c,e] (64x128), K = 128 (d)
    f32x4 accG[2][4] = {};
    #pragma unroll
    for (int ks = 0; ks < 4; ++ks) {
        bf16x8 a[2], bfr[4];
        #pragma unroll
        for (int m = 0; m < 2; ++m) {
            int row = wr * 32 + m * 16 + l15;
            int c16 = ks * 4 + l4;
            a[m] = *(const bf16x8*)(Ta + row * 128 + ((c16 ^ (row & 7)) * 8));
        }
        #pragma unroll
        for (int n = 0; n < 4; ++n) {
            int e = wc * 64 + n * 16 + l15;
            int c16 = ks * 4 + l4;
            bfr[n] = *(const bf16x8*)(Wb + e * 128 + ((c16 ^ (e & 7)) * 8));
        }
        #pragma unroll
        for (int m = 0; m < 2; ++m)
            #pragma unroll
            for (int n = 0; n < 4; ++n)
                accG[m][n] = __builtin_amdgcn_mfma_f32_16x16x32_bf16(
                    a[m], bfr[n], accG[m][n], 0, 0, 0);
    }

    // bP[c] = sum_d b[128+d] * Tcat[c,d]
    float bsum = 0.0f;
    {
        int c_l = tid >> 2, q = tid & 3;
        #pragma unroll
        for (int dd = 0; dd < 32; ++dd) {
            int d = q * 32 + dd;
            u16 tv = Ta[c_l * 128 + (((d >> 3) ^ (c_l & 7)) * 8) + (d & 7)];
            bsum += b2f(tv) * bias[128 + d];
        }
        bsum += __shfl_xor(bsum, 1);
        bsum += __shfl_xor(bsum, 2);
    }
    __syncthreads();

    // write G -> Wb; stage X tile -> Ta; write bP
    #pragma unroll
    for (int m = 0; m < 2; ++m)
        #pragma unroll
        for (int n = 0; n < 4; ++n)
            #pragma unroll
            for (int rr = 0; rr < 4; ++rr) {
                int c_l = wr * 32 + m * 16 + l4 * 4 + rr;
                int e   = wc * 64 + n * 16 + l15;
                Wb[c_l * 128 + (((e >> 3) ^ (c_l & 7)) * 8) + (e & 7)] =
                    f2bf(accG[m][n][rr]);
            }
    #pragma unroll
    for (int r0 = 0; r0 < 4; ++r0) {
        int unit = r0 * 256 + tid;
        int row = unit >> 4, c16 = unit & 15;
        const float* ga = features + (size_t)(bm + row) * D + c16 * 8;
        float4 a0 = *(const float4*)ga;
        float4 a1 = *(const float4*)(ga + 4);
        u16 h[8] = {f2bf(a0.x), f2bf(a0.y), f2bf(a0.z), f2bf(a0.w),
                    f2bf(a1.x), f2bf(a1.y), f2bf(a1.z), f2bf(a1.w)};
        *(bf16x8*)(Ta + row * 128 + ((c16 ^ (row & 7)) * 8)) = *(bf16x8*)h;
    }
    if ((tid & 3) == 0) bPl[tid >> 2] = bsum;
    __syncthreads();

    // P-GEMM: P[i,c] (64x64), K = 128 (e)
    f32x4 acc[2][2] = {};
    #pragma unroll
    for (int ks = 0; ks < 4; ++ks) {
        bf16x8 a[2], bq[2];
        #pragma unroll
        for (int m = 0; m < 2; ++m) {
            int row = wr * 32 + m * 16 + l15;
            int c16 = ks * 4 + l4;
            a[m] = *(const bf16x8*)(Ta + row * 128 + ((c16 ^ (row & 7)) * 8));
        }
        #pragma unroll
        for (int n = 0; n < 2; ++n) {
            int crow = wc * 32 + n * 16 + l15;
            int c16 = ks * 4 + l4;
            bq[n] = *(const bf16x8*)(Wb + crow * 128 + ((c16 ^ (crow & 7)) * 8));
        }
        #pragma unroll
        for (int m = 0; m < 2; ++m)
            #pragma unroll
            for (int n = 0; n < 2; ++n)
                acc[m][n] = __builtin_amdgcn_mfma_f32_16x16x32_bf16(
                    a[m], bq[n], acc[m][n], 0, 0, 0);
    }
    #pragma unroll
    for (int m = 0; m < 2; ++m)
        #pragma unroll
        for (int n = 0; n < 2; ++n)
            #pragma unroll
            for (int rr = 0; rr < 4; ++rr) {
                int grow = bm + wr * 32 + m * 16 + l4 * 4 + rr;
                int gcol = bn + wc * 32 + n * 16 + l15;
                int c_l  = wc * 32 + n * 16 + l15;
                if (gcol < PLD)
                    Pb[(size_t)grow * PLD + gcol] =
                        f2bf((acc[m][n][rr] + bPl[c_l]) * SQRT_D_INV);
            }
}

// ------------------------------------------------------------------
// flash_kernel: grid (64,8), 512 threads (8 waves) -> 16 waves/CU.
// Wave w: QK for j-subchunk bn+w*16; PV for d-slice w*16.
// Fence-free last-arriver reduce (same-XCD L2, R9-proven).
// ------------------------------------------------------------------
__global__ __launch_bounds__(512) void flash_kernel(
    const u16* __restrict__ qb,   // 1024x128 (pre-scaled)
    const u16* __restrict__ kb,   // 1024x128
    const u16* __restrict__ vT,   // 128x1024
    const u16* __restrict__ Pb,   // 1024x1200 bf16 (pre-scaled)
    const float* __restrict__ vd, // 1024x1024x3
    float* __restrict__ part,     // [64][8][16][128]
    float* __restrict__ rowsumC,  // [64][8][16]
    unsigned* __restrict__ cnt,   // [64]
    float* __restrict__ out)      // [1024][128]
{
    __shared__ __align__(16) u16 Pl[2560 * 8];   // 16x1200 + pad (40.96 KB)
    __shared__ __align__(16) u16 Ps[16 * 128];
    __shared__ float rsw[8][16];
    __shared__ int lastflag;
    const int tid = threadIdx.x;
    const int w = tid >> 6, lane = tid & 63;
    const int l15 = lane & 15, l4 = lane >> 4;
    const int it = blockIdx.x;          // i tile 0..63
    const int chunk = blockIdx.y;       // 0..7
    const int bm = it * 16;
    const int bn = chunk * 128;

    // ---- stage P slab: 2400 16B units, 5 rounds x 512, clamped tail ----
    const u16* Pg = Pb + (size_t)bm * PLD;
    #pragma unroll
    for (int r0 = 0; r0 < 5; ++r0) {
        int unit = r0 * 512 + tid;
        int cu = unit > 2399 ? 2399 : unit;
        __builtin_amdgcn_global_load_lds(
            (const GLOBAL_AS unsigned int*)(Pg + cu * 8),
            (LDS_AS unsigned int*)(Pl + r0 * 4096 + w * 512), 16, 0, 0);
    }

    // ---- early vd loads: i = l4*4+r, j = bn + w*16 + l15 ----
    float vx[4], vy[4], vz[4];
    #pragma unroll
    for (int r = 0; r < 4; ++r) {
        int i = l4 * 4 + r;
        int j = bn + w * 16 + l15;
        const float* vp = vd + ((size_t)(bm + i) * N_PTS + j) * 3;
        vx[r] = vp[0]; vy[r] = vp[1]; vz[r] = vp[2];
    }

    // ---- QK^T: wave w covers 16 j ----
    bf16x8 aq[4];
    #pragma unroll
    for (int ks = 0; ks < 4; ++ks)
        aq[ks] = *(const bf16x8*)(qb + (size_t)(bm + l15) * D + ks * 32 + l4 * 8);
    f32x4 acc = {};
    {
        int jt = bn + w * 16;
        #pragma unroll
        for (int ks = 0; ks < 4; ++ks) {
            bf16x8 bk = *(const bf16x8*)(kb + (size_t)(jt + l15) * D + ks * 32 + l4 * 8);
            acc = __builtin_amdgcn_mfma_f32_16x16x32_bf16(aq[ks], bk, acc, 0, 0, 0);
        }
    }
    __syncthreads();   // Pl staged

    // ---- bias gather + exp + Ps + rowsum ----
    float rs[4];
    #pragma unroll
    for (int r = 0; r < 4; ++r) {
        int i = l4 * 4 + r;
        int jl = w * 16 + l15;
        int ix = (int)floorf((vx[r] + 4.0f) * 50.0f);
        int iy = (int)floorf((vy[r] + 4.0f) * 50.0f);
        int iz = (int)floorf((vz[r] + 4.0f) * 50.0f);
        ix = min(max(ix, 0), QL - 1);
        iy = min(max(iy, 0), QL - 1);
        iz = min(max(iz, 0), QL - 1);
        const u16* Pr = Pl + i * PLD;
        float bv = b2f(Pr[ix]) + b2f(Pr[QL + iy]) + b2f(Pr[2 * QL + iz]);
        float e = __expf(acc[r] + bv);
        rs[r] = e;
        Ps[i * 128 + (((jl >> 3) ^ (i & 7)) * 8) + (jl & 7)] = f2bf(e);
    }
    #pragma unroll
    for (int r = 0; r < 4; ++r)
        #pragma unroll
        for (int off = 1; off < 16; off <<= 1)
            rs[r] += __shfl_xor(rs[r], off);
    if (l15 == 0)
        #pragma unroll
        for (int r = 0; r < 4; ++r) rsw[w][l4 * 4 + r] = rs[r];
    __syncthreads();
    if (tid < 16) {
        float s = 0.0f;
        #pragma unroll
        for (int z = 0; z < 8; ++z) s += rsw[z][tid];
        rowsumC[(it * 8 + chunk) * 16 + tid] = s;
    }

    // ---- PV: wave w owns d-slice [w*16, w*16+16), K = 128 j ----
    const int dt = w * 16;
    f32x4 acc2 = {};
    #pragma unroll
    for (int kt = 0; kt < 4; ++kt) {
        bf16x8 pa = *(const bf16x8*)(Ps + l15 * 128 + (((kt * 4 + l4) ^ (l15 & 7)) * 8));
        bf16x8 bv8 = *(const bf16x8*)(vT + (size_t)(dt + l15) * N_PTS + bn + kt * 32 + l4 * 8);
        acc2 = __builtin_amdgcn_mfma_f32_16x16x32_bf16(pa, bv8, acc2, 0, 0, 0);
    }
    float* po = part + (size_t)(it * 8 + chunk) * (16 * D);
    #pragma unroll
    for (int r = 0; r < 4; ++r)
        po[(l4 * 4 + r) * D + dt + l15] = acc2[r];

    // ---- fence-free last-arriver reduce (same-XCD L2 visibility) ----
    asm volatile("s_waitcnt vmcnt(0)" ::: "memory");
    __syncthreads();
    if (tid == 0) {
        unsigned old = __hip_atomic_fetch_add(
            &cnt[it], 1u, __ATOMIC_RELAXED, __HIP_MEMORY_SCOPE_AGENT);
        lastflag = (old == 7u);
    }
    __syncthreads();
    if (lastflag) {
        const float4* p4 = (const float4*)(part + (size_t)it * 8 * 16 * D);
        const float* rsb = rowsumC + it * 8 * 16;
        int f4 = tid;                      // 0..511 = 16 rows x 32 f4
        int row = f4 >> 5;
        float rsum = 0.0f;
        #pragma unroll
        for (int z = 0; z < 8; ++z) rsum += rsb[z * 16 + row];
        float inv = 1.0f / rsum;
        float4 a = p4[f4];
        #pragma unroll
        for (int z = 1; z < 8; ++z) {
            float4 v = p4[z * 512 + f4];
            a.x += v.x; a.y += v.y; a.z += v.z; a.w += v.w;
        }
        a.x *= inv; a.y *= inv; a.z *= inv; a.w *= inv;
        ((float4*)out)[bm * 32 + f4] = a;
    }
}

// ------------------------------------------------------------------
extern "C" void kernel_launch(void* const* d_in, const int* in_sizes, int n_in,
                              void* d_out, int out_size, void* d_ws, size_t ws_size,
                              hipStream_t stream)
{
    const float* features = (const float*)d_in[0];  // 1024 x 128
    const float* vd       = (const float*)d_in[1];  // 1024 x 1024 x 3
    const float* W        = (const float*)d_in[2];  // 128 x 384
    const float* b        = (const float*)d_in[3];  // 384
    const float* tx       = (const float*)d_in[4];  // 3 x 400 x 128
    const float* ty       = (const float*)d_in[5];
    const float* tz       = (const float*)d_in[6];
    float* out = (float*)d_out;                     // 1024 x 128 f32

    char* w0 = (char*)d_ws;
    unsigned* cnt = (unsigned*)w0;                  // 256 B  [64]
    u16* qb       = (u16*)(w0 + 0x1000);            // 256 KB
    u16* kb       = (u16*)(w0 + 0x50000);           // 256 KB
    u16* vT       = (u16*)(w0 + 0x90000);           // 256 KB (128x1024)
    u16* Pb       = (u16*)(w0 + 0xD0000);           // 2.4 MB (1024x1200 bf16)
    float* part   = (float*)(w0 + 0x330000);        // 4 MB   [64][8][16][128]
    float* rowsumC= (float*)(w0 + 0x730000);        // 32 KB  [64][8][16]

    // 1. qkv (192 blocks) + P (304 blocks), one dispatch; zeroes cnt
    prep2_kernel<<<dim3(496), dim3(256), 0, stream>>>(
        features, W, b, tx, ty, tz, qb, kb, vT, Pb, cnt);

    // 2. flash (512 threads, 16 waves/CU) + last-arriver reduce
    flash_kernel<<<dim3(64, 8), dim3(512), 0, stream>>>(
        qb, kb, vT, Pb, vd, part, rowsumC, cnt, out);
}

// Round 12
// 23.515 us; speedup vs baseline: 1.0737x; 1.0737x over previous
//
#include <hip/hip_runtime.h>
#include <math.h>

#define N_PTS 1024
#define D 128
#define QL 400
#define PLD 1200            // 3*QL
#define SQRT_D_INV 0.08838834764831845f

typedef __attribute__((ext_vector_type(8))) short bf16x8;
typedef __attribute__((ext_vector_type(4))) float f32x4;
typedef unsigned short u16;

#define GLOBAL_AS __attribute__((address_space(1)))
#define LDS_AS    __attribute__((address_space(3)))

__device__ __forceinline__ u16 f2bf(float x) {
    union { float f; unsigned u; } v; v.f = x;
    unsigned r = v.u + 0x7fff + ((v.u >> 16) & 1);   // RNE
    return (u16)(r >> 16);
}
__device__ __forceinline__ float b2f(u16 h) {
    union { unsigned u; float f; } v; v.u = ((unsigned)h) << 16;
    return v.f;
}

// ------------------------------------------------------------------
// prep2_kernel (R10-proven, exact): ONE dispatch, two roles:
//  blocks [0,96):   qkv = features@W + b -> qb(1/sqrtD)/kb/vT
//  blocks [96,400): P-role: G-tile = Tcat@Wk^T local; P = X@G^T + bP
// ------------------------------------------------------------------
__global__ __launch_bounds__(256) void prep2_kernel(
    const float* __restrict__ features, const float* __restrict__ W,
    const float* __restrict__ bias,
    const float* __restrict__ tx, const float* __restrict__ ty,
    const float* __restrict__ tz,
    u16* __restrict__ qb, u16* __restrict__ kb, u16* __restrict__ vT,
    u16* __restrict__ Pb, unsigned* __restrict__ cnt)
{
    __shared__ __align__(16) u16 smem[24704];   // 49.4 KB
    const int tid = threadIdx.x;
    const int bx = blockIdx.x;
    const int wave = tid >> 6, lane = tid & 63;
    const int wr = wave >> 1, wc = wave & 1;
    const int l15 = lane & 15, l4 = lane >> 4;

    if (bx == 0 && tid < 64) cnt[tid] = 0u;

    if (bx < 96) {
        // ---------------- qkv role ----------------
        u16* As = smem;
        u16* Bs = smem + 8192;
        const int bm = (bx / 6) * 64;
        const int bn = (bx % 6) * 64;

        #pragma unroll
        for (int r0 = 0; r0 < 4; ++r0) {
            int unit = r0 * 256 + tid;
            int row = unit >> 4, c16 = unit & 15;
            const float* ga = features + (size_t)(bm + row) * D + c16 * 8;
            float4 a0 = *(const float4*)ga;
            float4 a1 = *(const float4*)(ga + 4);
            u16 h[8] = {f2bf(a0.x), f2bf(a0.y), f2bf(a0.z), f2bf(a0.w),
                        f2bf(a1.x), f2bf(a1.y), f2bf(a1.z), f2bf(a1.w)};
            *(bf16x8*)(As + row * 128 + ((c16 ^ (row & 7)) * 8)) = *(bf16x8*)h;
        }
        #pragma unroll
        for (int r2 = 0; r2 < 8; ++r2) {
            int k = r2 * 16 + (tid >> 4);
            int nl = (tid & 15) * 4;
            float4 w4 = *(const float4*)&W[(size_t)k * 384 + bn + nl];
            float wv[4] = {w4.x, w4.y, w4.z, w4.w};
            #pragma unroll
            for (int e = 0; e < 4; ++e) {
                int n = nl + e;
                Bs[n * 128 + (((k >> 3) ^ (n & 7)) << 3) + (k & 7)] = f2bf(wv[e]);
            }
        }
        __syncthreads();

        f32x4 acc[2][2] = {};
        #pragma unroll
        for (int ks = 0; ks < 4; ++ks) {
            bf16x8 a[2], b[2];
            #pragma unroll
            for (int m = 0; m < 2; ++m) {
                int row = wr * 32 + m * 16 + l15;
                int c16 = ks * 4 + l4;
                a[m] = *(const bf16x8*)(As + row * 128 + ((c16 ^ (row & 7)) * 8));
            }
            #pragma unroll
            for (int n = 0; n < 2; ++n) {
                int row = wc * 32 + n * 16 + l15;
                int c16 = ks * 4 + l4;
                b[n] = *(const bf16x8*)(Bs + row * 128 + ((c16 ^ (row & 7)) * 8));
            }
            #pragma unroll
            for (int m = 0; m < 2; ++m)
                #pragma unroll
                for (int n = 0; n < 2; ++n)
                    acc[m][n] = __builtin_amdgcn_mfma_f32_16x16x32_bf16(
                        a[m], b[n], acc[m][n], 0, 0, 0);
        }

        #pragma unroll
        for (int m = 0; m < 2; ++m)
            #pragma unroll
            for (int n = 0; n < 2; ++n)
                #pragma unroll
                for (int r = 0; r < 4; ++r) {
                    int grow = bm + wr * 32 + m * 16 + l4 * 4 + r;
                    int gcol = bn + wc * 32 + n * 16 + l15;
                    float val = acc[m][n][r] + bias[gcol];
                    int reg = gcol >> 7, lc = gcol & 127;
                    if (reg == 0)      qb[grow * D + lc] = f2bf(val * SQRT_D_INV);
                    else if (reg == 1) kb[grow * D + lc] = f2bf(val);
                    else               vT[(size_t)lc * N_PTS + grow] = f2bf(val);
                }
        return;
    }

    // ---------------- P role ----------------
    const int t = bx - 96;
    const int ib = t / 19, jb = t % 19;
    const int bm = ib * 64, bn = jb * 64;
    u16* Ta = smem;                         // Tcat tile 64x128; later X tile
    u16* Wb = smem + 8192;                  // Wk 128x128; later G 64x128
    float* bPl = (float*)(smem + 24576);    // 64 f32

    #pragma unroll
    for (int r0 = 0; r0 < 4; ++r0) {
        int unit = r0 * 256 + tid;
        int row = unit >> 4, c16 = unit & 15;
        int c = bn + row; if (c > PLD - 1) c = PLD - 1;
        int sec = c / QL, rr = c - sec * QL;
        const float* tsec = (sec == 0) ? tx : ((sec == 1) ? ty : tz);
        const float* ga = tsec + QL * D + rr * D + c16 * 8;
        float4 a0 = *(const float4*)ga;
        float4 a1 = *(const float4*)(ga + 4);
        u16 h[8] = {f2bf(a0.x), f2bf(a0.y), f2bf(a0.z), f2bf(a0.w),
                    f2bf(a1.x), f2bf(a1.y), f2bf(a1.z), f2bf(a1.w)};
        *(bf16x8*)(Ta + row * 128 + ((c16 ^ (row & 7)) * 8)) = *(bf16x8*)h;
    }
    #pragma unroll
    for (int r0 = 0; r0 < 8; ++r0) {
        int unit = r0 * 256 + tid;
        int e = unit >> 4, c16 = unit & 15;
        const float* ga = W + (size_t)e * 384 + 128 + c16 * 8;
        float4 a0 = *(const float4*)ga;
        float4 a1 = *(const float4*)(ga + 4);
        u16 h[8] = {f2bf(a0.x), f2bf(a0.y), f2bf(a0.z), f2bf(a0.w),
                    f2bf(a1.x), f2bf(a1.y), f2bf(a1.z), f2bf(a1.w)};
        *(bf16x8*)(Wb + e * 128 + ((c16 ^ (e & 7)) * 8)) = *(bf16x8*)h;
    }
    __syncthreads();

    // G-GEMM: G[c,e] (64x128), K = 128 (d)
    f32x4 accG[2][4] = {};
    #pragma unroll
    for (int ks = 0; ks < 4; ++ks) {
        bf16x8 a[2], bfr[4];
        #pragma unroll
        for (int m = 0; m < 2; ++m) {
            int row = wr * 32 + m * 16 + l15;
            int c16 = ks * 4 + l4;
            a[m] = *(const bf16x8*)(Ta + row * 128 + ((c16 ^ (row & 7)) * 8));
        }
        #pragma unroll
        for (int n = 0; n < 4; ++n) {
            int e = wc * 64 + n * 16 + l15;
            int c16 = ks * 4 + l4;
            bfr[n] = *(const bf16x8*)(Wb + e * 128 + ((c16 ^ (e & 7)) * 8));
        }
        #pragma unroll
        for (int m = 0; m < 2; ++m)
            #pragma unroll
            for (int n = 0; n < 4; ++n)
                accG[m][n] = __builtin_amdgcn_mfma_f32_16x16x32_bf16(
                    a[m], bfr[n], accG[m][n], 0, 0, 0);
    }

    // bP[c] = sum_d b[128+d] * Tcat[c,d]
    float bsum = 0.0f;
    {
        int c_l = tid >> 2, q = tid & 3;
        #pragma unroll
        for (int dd = 0; dd < 32; ++dd) {
            int d = q * 32 + dd;
            u16 tv = Ta[c_l * 128 + (((d >> 3) ^ (c_l & 7)) * 8) + (d & 7)];
            bsum += b2f(tv) * bias[128 + d];
        }
        bsum += __shfl_xor(bsum, 1);
        bsum += __shfl_xor(bsum, 2);
    }
    __syncthreads();

    // write G -> Wb; stage X tile -> Ta; write bP
    #pragma unroll
    for (int m = 0; m < 2; ++m)
        #pragma unroll
        for (int n = 0; n < 4; ++n)
            #pragma unroll
            for (int rr = 0; rr < 4; ++rr) {
                int c_l = wr * 32 + m * 16 + l4 * 4 + rr;
                int e   = wc * 64 + n * 16 + l15;
                Wb[c_l * 128 + (((e >> 3) ^ (c_l & 7)) * 8) + (e & 7)] =
                    f2bf(accG[m][n][rr]);
            }
    #pragma unroll
    for (int r0 = 0; r0 < 4; ++r0) {
        int unit = r0 * 256 + tid;
        int row = unit >> 4, c16 = unit & 15;
        const float* ga = features + (size_t)(bm + row) * D + c16 * 8;
        float4 a0 = *(const float4*)ga;
        float4 a1 = *(const float4*)(ga + 4);
        u16 h[8] = {f2bf(a0.x), f2bf(a0.y), f2bf(a0.z), f2bf(a0.w),
                    f2bf(a1.x), f2bf(a1.y), f2bf(a1.z), f2bf(a1.w)};
        *(bf16x8*)(Ta + row * 128 + ((c16 ^ (row & 7)) * 8)) = *(bf16x8*)h;
    }
    if ((tid & 3) == 0) bPl[tid >> 2] = bsum;
    __syncthreads();

    // P-GEMM: P[i,c] (64x64), K = 128 (e)
    f32x4 acc[2][2] = {};
    #pragma unroll
    for (int ks = 0; ks < 4; ++ks) {
        bf16x8 a[2], bq[2];
        #pragma unroll
        for (int m = 0; m < 2; ++m) {
            int row = wr * 32 + m * 16 + l15;
            int c16 = ks * 4 + l4;
            a[m] = *(const bf16x8*)(Ta + row * 128 + ((c16 ^ (row & 7)) * 8));
        }
        #pragma unroll
        for (int n = 0; n < 2; ++n) {
            int crow = wc * 32 + n * 16 + l15;
            int c16 = ks * 4 + l4;
            bq[n] = *(const bf16x8*)(Wb + crow * 128 + ((c16 ^ (crow & 7)) * 8));
        }
        #pragma unroll
        for (int m = 0; m < 2; ++m)
            #pragma unroll
            for (int n = 0; n < 2; ++n)
                acc[m][n] = __builtin_amdgcn_mfma_f32_16x16x32_bf16(
                    a[m], bq[n], acc[m][n], 0, 0, 0);
    }
    #pragma unroll
    for (int m = 0; m < 2; ++m)
        #pragma unroll
        for (int n = 0; n < 2; ++n)
            #pragma unroll
            for (int rr = 0; rr < 4; ++rr) {
                int grow = bm + wr * 32 + m * 16 + l4 * 4 + rr;
                int gcol = bn + wc * 32 + n * 16 + l15;
                int c_l  = wc * 32 + n * 16 + l15;
                if (gcol < PLD)
                    Pb[(size_t)grow * PLD + gcol] =
                        f2bf((acc[m][n][rr] + bPl[c_l]) * SQRT_D_INV);
            }
}

// ------------------------------------------------------------------
// flash_kernel (R10 structure, 256 threads) + T14 hoist: all 8 vT
// fragment loads issued right after QK^T, so their L2 latency hides
// under the Pl wait + gather + exp + rowsum section.
// Fence-free last-arriver reduce (same-XCD L2, R9-proven).
// ------------------------------------------------------------------
__global__ __launch_bounds__(256) void flash_kernel(
    const u16* __restrict__ qb,   // 1024x128 (pre-scaled)
    const u16* __restrict__ kb,   // 1024x128
    const u16* __restrict__ vT,   // 128x1024
    const u16* __restrict__ Pb,   // 1024x1200 bf16 (pre-scaled)
    const float* __restrict__ vd, // 1024x1024x3
    float* __restrict__ part,     // [64][8][16][128]
    float* __restrict__ rowsumC,  // [64][8][16]
    unsigned* __restrict__ cnt,   // [64]
    float* __restrict__ out)      // [1024][128]
{
    __shared__ __align__(16) u16 Pl[2432 * 8];   // 16x1200 + pad
    __shared__ __align__(16) u16 Ps[16 * 128];
    __shared__ float rsw[4][16];
    __shared__ int lastflag;
    const int tid = threadIdx.x;
    const int wave = tid >> 6, lane = tid & 63;
    const int l15 = lane & 15, l4 = lane >> 4;
    const int it = blockIdx.x;          // i tile 0..63
    const int chunk = blockIdx.y;       // 0..7
    const int bm = it * 16;
    const int bn = chunk * 128;

    // ---- stage P slab ----
    const u16* Pg = Pb + (size_t)bm * PLD;
    #pragma unroll
    for (int r0 = 0; r0 < 9; ++r0) {
        int unit = r0 * 256 + tid;
        __builtin_amdgcn_global_load_lds(
            (const GLOBAL_AS unsigned int*)(Pg + unit * 8),
            (LDS_AS unsigned int*)(Pl + r0 * 2048 + wave * 512), 16, 0, 0);
    }
    if (wave < 2) {
        int unit = 9 * 256 + tid;
        int cu = unit > 2399 ? 2399 : unit;
        __builtin_amdgcn_global_load_lds(
            (const GLOBAL_AS unsigned int*)(Pg + cu * 8),
            (LDS_AS unsigned int*)(Pl + 9 * 2048 + wave * 512), 16, 0, 0);
    }

    // ---- early vd loads ----
    float vx[2][4], vy[2][4], vz[2][4];
    #pragma unroll
    for (int nn = 0; nn < 2; ++nn)
        #pragma unroll
        for (int r = 0; r < 4; ++r) {
            int i = l4 * 4 + r;
            int j = wave * 32 + nn * 16 + l15;
            const float* vp = vd + ((size_t)(bm + i) * N_PTS + bn + j) * 3;
            vx[nn][r] = vp[0]; vy[nn][r] = vp[1]; vz[nn][r] = vp[2];
        }

    // ---- QK^T ----
    bf16x8 aq[4];
    #pragma unroll
    for (int ks = 0; ks < 4; ++ks)
        aq[ks] = *(const bf16x8*)(qb + (size_t)(bm + l15) * D + ks * 32 + l4 * 8);
    f32x4 acc[2] = {};
    #pragma unroll
    for (int nn = 0; nn < 2; ++nn) {
        int jt = bn + wave * 32 + nn * 16;
        #pragma unroll
        for (int ks = 0; ks < 4; ++ks) {
            bf16x8 bk = *(const bf16x8*)(kb + (size_t)(jt + l15) * D + ks * 32 + l4 * 8);
            acc[nn] = __builtin_amdgcn_mfma_f32_16x16x32_bf16(aq[ks], bk, acc[nn], 0, 0, 0);
        }
    }

    // ---- T14: hoist ALL vT fragment loads (independent of LDS state) ----
    bf16x8 vb[2][4];
    #pragma unroll
    for (int nn = 0; nn < 2; ++nn) {
        int dt = wave * 32 + nn * 16;
        #pragma unroll
        for (int kt = 0; kt < 4; ++kt)
            vb[nn][kt] = *(const bf16x8*)(vT + (size_t)(dt + l15) * N_PTS + bn + kt * 32 + l4 * 8);
    }

    __syncthreads();   // Pl staged

    // ---- bias gather + exp + Ps + rowsum ----
    float rs[4] = {0.f, 0.f, 0.f, 0.f};
    #pragma unroll
    for (int nn = 0; nn < 2; ++nn)
        #pragma unroll
        for (int r = 0; r < 4; ++r) {
            int i = l4 * 4 + r;
            int jl = wave * 32 + nn * 16 + l15;
            int ix = (int)floorf((vx[nn][r] + 4.0f) * 50.0f);
            int iy = (int)floorf((vy[nn][r] + 4.0f) * 50.0f);
            int iz = (int)floorf((vz[nn][r] + 4.0f) * 50.0f);
            ix = min(max(ix, 0), QL - 1);
            iy = min(max(iy, 0), QL - 1);
            iz = min(max(iz, 0), QL - 1);
            const u16* Pr = Pl + i * PLD;
            float bv = b2f(Pr[ix]) + b2f(Pr[QL + iy]) + b2f(Pr[2 * QL + iz]);
            float e = __expf(acc[nn][r] + bv);
            rs[r] += e;
            Ps[i * 128 + (((jl >> 3) ^ (i & 7)) * 8) + (jl & 7)] = f2bf(e);
        }
    #pragma unroll
    for (int r = 0; r < 4; ++r)
        #pragma unroll
        for (int off = 1; off < 16; off <<= 1)
            rs[r] += __shfl_xor(rs[r], off);
    if (l15 == 0)
        #pragma unroll
        for (int r = 0; r < 4; ++r) rsw[wave][l4 * 4 + r] = rs[r];
    __syncthreads();
    if (tid < 16)
        rowsumC[(it * 8 + chunk) * 16 + tid] =
            rsw[0][tid] + rsw[1][tid] + rsw[2][tid] + rsw[3][tid];

    // ---- PV (vT already in registers) ----
    bf16x8 pa[4];
    #pragma unroll
    for (int kt = 0; kt < 4; ++kt)
        pa[kt] = *(const bf16x8*)(Ps + l15 * 128 + (((kt * 4 + l4) ^ (l15 & 7)) * 8));
    f32x4 acc2[2] = {};
    #pragma unroll
    for (int nn = 0; nn < 2; ++nn)
        #pragma unroll
        for (int kt = 0; kt < 4; ++kt)
            acc2[nn] = __builtin_amdgcn_mfma_f32_16x16x32_bf16(pa[kt], vb[nn][kt], acc2[nn], 0, 0, 0);

    float* po = part + (size_t)(it * 8 + chunk) * (16 * D);
    #pragma unroll
    for (int nn = 0; nn < 2; ++nn)
        #pragma unroll
        for (int r = 0; r < 4; ++r)
            po[(l4 * 4 + r) * D + wave * 32 + nn * 16 + l15] = acc2[nn][r];

    // ---- fence-free last-arriver reduce (same-XCD L2 visibility) ----
    asm volatile("s_waitcnt vmcnt(0)" ::: "memory");
    __syncthreads();
    if (tid == 0) {
        unsigned old = __hip_atomic_fetch_add(
            &cnt[it], 1u, __ATOMIC_RELAXED, __HIP_MEMORY_SCOPE_AGENT);
        lastflag = (old == 7u);
    }
    __syncthreads();
    if (lastflag) {
        const float4* p4 = (const float4*)(part + (size_t)it * 8 * 16 * D);
        const float* rsb = rowsumC + it * 8 * 16;
        #pragma unroll
        for (int h = 0; h < 2; ++h) {
            int f4 = h * 256 + tid;            // 0..511 (16 rows x 32 f4)
            int row = f4 >> 5;
            float rsum = 0.0f;
            #pragma unroll
            for (int z = 0; z < 8; ++z) rsum += rsb[z * 16 + row];
            float inv = 1.0f / rsum;
            float4 a = p4[f4];
            #pragma unroll
            for (int z = 1; z < 8; ++z) {
                float4 v = p4[z * 512 + f4];
                a.x += v.x; a.y += v.y; a.z += v.z; a.w += v.w;
            }
            a.x *= inv; a.y *= inv; a.z *= inv; a.w *= inv;
            ((float4*)out)[bm * 32 + f4] = a;
        }
    }
}

// ------------------------------------------------------------------
extern "C" void kernel_launch(void* const* d_in, const int* in_sizes, int n_in,
                              void* d_out, int out_size, void* d_ws, size_t ws_size,
                              hipStream_t stream)
{
    const float* features = (const float*)d_in[0];  // 1024 x 128
    const float* vd       = (const float*)d_in[1];  // 1024 x 1024 x 3
    const float* W        = (const float*)d_in[2];  // 128 x 384
    const float* b        = (const float*)d_in[3];  // 384
    const float* tx       = (const float*)d_in[4];  // 3 x 400 x 128
    const float* ty       = (const float*)d_in[5];
    const float* tz       = (const float*)d_in[6];
    float* out = (float*)d_out;                     // 1024 x 128 f32

    char* w0 = (char*)d_ws;
    unsigned* cnt = (unsigned*)w0;                  // 256 B  [64]
    u16* qb       = (u16*)(w0 + 0x1000);            // 256 KB
    u16* kb       = (u16*)(w0 + 0x50000);           // 256 KB
    u16* vT       = (u16*)(w0 + 0x90000);           // 256 KB (128x1024)
    u16* Pb       = (u16*)(w0 + 0xD0000);           // 2.4 MB (1024x1200 bf16)
    float* part   = (float*)(w0 + 0x330000);        // 4 MB   [64][8][16][128]
    float* rowsumC= (float*)(w0 + 0x730000);        // 32 KB  [64][8][16]

    dim3 blk(256);

    // 1. qkv + P (independent roles, one dispatch; zeroes cnt)
    prep2_kernel<<<dim3(400), blk, 0, stream>>>(
        features, W, b, tx, ty, tz, qb, kb, vT, Pb, cnt);

    // 2. flash (vT hoisted) + fence-free last-arriver reduce/normalize
    flash_kernel<<<dim3(64, 8), blk, 0, stream>>>(
        qb, kb, vT, Pb, vd, part, rowsumC, cnt, out);
}